// Round 4
// baseline (278.279 us; speedup 1.0000x reference)
//
#include <hip/hip_runtime.h>

// 2 points per thread: point i0 = base+t and i1 = base+256+t (both load
// groups fully coalesced). All 18 load instructions are issued before any
// use so each wave keeps ~2x the cache lines in flight -> attacks the
// MLP*latency bound (R2/R3 proved store/load *patterns* are neutral).
// Stores are nontemporal: out is write-once, never read.

__global__ __launch_bounds__(256) void cov_proj_kernel(
    const float4* __restrict__ rot,     // (N,4) as float4
    const float*  __restrict__ mod,     // (1,)
    const float2* __restrict__ scale,   // (N,2) as float2
    const float*  __restrict__ p_k,     // (N,3)
    const float4* __restrict__ vm4,     // (N,16) viewed as float4[N*4]
    float*        __restrict__ out,     // (N,9)
    int n)
{
    const int t = threadIdx.x;
    const int base = blockIdx.x * 512;
    const int i0 = base + t;
    const int i1 = base + 256 + t;
    const bool a0 = i0 < n;
    const bool a1 = i1 < n;

    const float m = mod[0];

    // ---- Issue ALL loads first (max lines in flight per wave) ----
    float4 q0 = {}, q1 = {};
    float2 sc0 = {}, sc1 = {};
    float p00 = 0, p01 = 0, p02 = 0, p10 = 0, p11 = 0, p12 = 0;
    float4 v00 = {}, v01 = {}, v02 = {}, v03 = {};
    float4 v10 = {}, v11 = {}, v12 = {}, v13 = {};

    if (a0) {
        q0  = rot[i0];
        sc0 = scale[i0];
        p00 = p_k[3 * i0 + 0];
        p01 = p_k[3 * i0 + 1];
        p02 = p_k[3 * i0 + 2];
        v00 = vm4[4 * i0 + 0];
        v01 = vm4[4 * i0 + 1];
        v02 = vm4[4 * i0 + 2];
        v03 = vm4[4 * i0 + 3];
    }
    if (a1) {
        q1  = rot[i1];
        sc1 = scale[i1];
        p10 = p_k[3 * i1 + 0];
        p11 = p_k[3 * i1 + 1];
        p12 = p_k[3 * i1 + 2];
        v10 = vm4[4 * i1 + 0];
        v11 = vm4[4 * i1 + 1];
        v12 = vm4[4 * i1 + 2];
        v13 = vm4[4 * i1 + 3];
    }

#define COMPUTE_STORE(q, sc, P0, P1, P2, VM0, VM1, VM2, VM3, I)                 \
    {                                                                           \
        float r = q.x, x = q.y, y = q.z, z = q.w;                               \
        float s0 = m * sc.x;                                                    \
        float s1 = m * sc.y;                                                    \
        float R00 = 1.0f - 2.0f * (y * y + z * z);                              \
        float R10 = 2.0f * (x * y + r * z);                                     \
        float R20 = 2.0f * (x * z - r * y);                                     \
        float R01 = 2.0f * (x * y - r * z);                                     \
        float R11 = 1.0f - 2.0f * (x * x + z * z);                              \
        float R21 = 2.0f * (y * z + r * x);                                     \
        float u0 = s0 * R00, u1 = s0 * R10, u2 = s0 * R20;                      \
        float v0 = s1 * R01, v1 = s1 * R11, v2 = s1 * R21;                      \
        float* o = out + (size_t)9 * (I);                                       \
        __builtin_nontemporal_store(VM0.x * u0 + VM1.x * u1 + VM2.x * u2, o + 0);\
        __builtin_nontemporal_store(VM0.x * v0 + VM1.x * v1 + VM2.x * v2, o + 1);\
        __builtin_nontemporal_store(VM0.x * P0 + VM1.x * P1 + VM2.x * P2 + VM3.x, o + 2);\
        __builtin_nontemporal_store(VM0.y * u0 + VM1.y * u1 + VM2.y * u2, o + 3);\
        __builtin_nontemporal_store(VM0.y * v0 + VM1.y * v1 + VM2.y * v2, o + 4);\
        __builtin_nontemporal_store(VM0.y * P0 + VM1.y * P1 + VM2.y * P2 + VM3.y, o + 5);\
        __builtin_nontemporal_store(VM0.z * u0 + VM1.z * u1 + VM2.z * u2, o + 6);\
        __builtin_nontemporal_store(VM0.z * v0 + VM1.z * v1 + VM2.z * v2, o + 7);\
        __builtin_nontemporal_store(VM0.z * P0 + VM1.z * P1 + VM2.z * P2 + VM3.z, o + 8);\
    }

    if (a0) COMPUTE_STORE(q0, sc0, p00, p01, p02, v00, v01, v02, v03, i0);
    if (a1) COMPUTE_STORE(q1, sc1, p10, p11, p12, v10, v11, v12, v13, i1);
#undef COMPUTE_STORE
}

extern "C" void kernel_launch(void* const* d_in, const int* in_sizes, int n_in,
                              void* d_out, int out_size, void* d_ws, size_t ws_size,
                              hipStream_t stream) {
    const float4* rot   = (const float4*)d_in[0];
    const float*  mod   = (const float*)d_in[1];
    const float2* scale = (const float2*)d_in[2];
    const float*  p_k   = (const float*)d_in[3];
    const float4* vm4   = (const float4*)d_in[4];
    float* out = (float*)d_out;

    int n = in_sizes[0] / 4;  // rot has N*4 elements
    int block = 256;
    int grid = (n + 511) / 512;  // 512 points per block (2 per thread)
    cov_proj_kernel<<<grid, block, 0, stream>>>(rot, mod, scale, p_k, vm4, out, n);
}